// Round 8
// baseline (1603.399 us; speedup 1.0000x reference)
//
#include <hip/hip_runtime.h>
#include <hip/hip_bf16.h>

#define NE 8
#define NT 512
#define DIN 7168
#define DINT 2048
#define BK 64

typedef __bf16 bf16x8 __attribute__((ext_vector_type(8)));
typedef float f32x4 __attribute__((ext_vector_type(4)));
typedef unsigned short ushort8v __attribute__((ext_vector_type(8)));

#define MFMA __builtin_amdgcn_mfma_f32_16x16x32_bf16

// XOR swizzle (T2): 16B granule within a 128B row XOR'd with row&7.
// row stride = 64 bf16 elements (128B).
__device__ __forceinline__ int swz(int row, int k) {
    return (row << 6) + (((k >> 3) ^ (row & 7)) << 3) + (k & 7);
}

__device__ __forceinline__ ushort4 cvt4(float4 v) {
    ushort4 h;
    h.x = __builtin_bit_cast(unsigned short, (__bf16)v.x);
    h.y = __builtin_bit_cast(unsigned short, (__bf16)v.y);
    h.z = __builtin_bit_cast(unsigned short, (__bf16)v.z);
    h.w = __builtin_bit_cast(unsigned short, (__bf16)v.w);
    return h;
}

// lgkm-only drain + raw barrier: outstanding global loads (vmcnt) stay in
// flight across the barrier (T4).
__device__ __forceinline__ void barrier_lgkm() {
    asm volatile("s_waitcnt lgkmcnt(0)" ::: "memory");
    __builtin_amdgcn_s_barrier();
}

// ---------------- Kernel A: gate+up ----------------
// BM=128 x BN=128, BK=64, 256 thr = 4 waves (2x2), wave-tile 64x64, dual acc.
// Single-buffer LDS 48 KB -> 2 blocks/CU (grid 512 = exactly 2/CU): cross-
// block overlap hides the stage/barrier serial section.
// Iter: issue x(t) -> write B1,B3(t) -> write A(t) -> issue w(t+1)
//       -> lgkm barrier -> compute(t) -> lgkm barrier.
__global__ __launch_bounds__(256, 2) void ffn_gate_up(
    const float* __restrict__ x, const float* __restrict__ w1,
    const float* __restrict__ b1, const float* __restrict__ w3,
    const float* __restrict__ b3, unsigned short* __restrict__ g) {
    __shared__ unsigned short As[128 * BK];   // 16 KB
    __shared__ unsigned short B1s[128 * BK];  // 16 KB
    __shared__ unsigned short B3s[128 * BK];  // 16 KB

    const int tid = threadIdx.x;
    const int lane = tid & 63;
    const int wave = tid >> 6;                // 0..3
    const int wm = wave >> 1, wn = wave & 1;  // wave tile 64x64
    const int e = blockIdx.z;
    const int bn = blockIdx.x * 128;
    const int bm = blockIdx.y * 128;

    const char* xb = (const char*)x + ((size_t)e * NT * DIN + (size_t)bm * DIN) * 4;
    const char* w1c = (const char*)w1 + ((size_t)e * DINT * DIN + (size_t)bn * DIN) * 4;
    const char* w3c = (const char*)w3 + ((size_t)e * DINT * DIN + (size_t)bn * DIN) * 4;

    const int srow = tid >> 4;        // 0..15
    const int scol = (tid & 15) * 4;  // 0..60
    const int swb = swz(srow, scol);  // p-invariant ((p*16+srow)&7 == srow&7)

    int xo[8];
#pragma unroll
    for (int p = 0; p < 8; ++p) xo[p] = ((p * 16 + srow) * DIN + scol) * 4;

    f32x4 acc1[4][4], acc3[4][4];
#pragma unroll
    for (int m = 0; m < 4; ++m)
#pragma unroll
        for (int n = 0; n < 4; ++n) {
            acc1[m][n] = (f32x4)0.0f;
            acc3[m][n] = (f32x4)0.0f;
        }

    float4 ra[8], rb1[8], rb3[8];

    // prologue: issue weight loads for tile 0
#pragma unroll
    for (int p = 0; p < 8; ++p) {
        rb1[p] = *(const float4*)(w1c + xo[p]);
        rb3[p] = *(const float4*)(w3c + xo[p]);
    }

    const int l15 = lane & 15;
    const int kf0 = (lane >> 4) << 3;
    const int NIT = DIN / BK;  // 112

    for (int t = 0; t < NIT; ++t) {
        const int kkB = t * BK * 4;
        // 1. issue x loads for tile t (L2/L3-hot; latency hides under B-writes)
#pragma unroll
        for (int p = 0; p < 8; ++p) ra[p] = *(const float4*)(xb + xo[p] + kkB);
        // 2. write B1,B3 tile t (regs landed during previous compute)
#pragma unroll
        for (int p = 0; p < 8; ++p) {
            *(ushort4*)&B1s[p * 1024 + swb] = cvt4(rb1[p]);
            *(ushort4*)&B3s[p * 1024 + swb] = cvt4(rb3[p]);
        }
        // 3. write A tile t
#pragma unroll
        for (int p = 0; p < 8; ++p) *(ushort4*)&As[p * 1024 + swb] = cvt4(ra[p]);
        // 4. issue weight loads for tile t+1 (fly across barrier + compute)
        const int kldB = ((t + 1 < NIT) ? (t + 1) : (NIT - 1)) * BK * 4;
#pragma unroll
        for (int p = 0; p < 8; ++p) {
            rb1[p] = *(const float4*)(w1c + xo[p] + kldB);
            rb3[p] = *(const float4*)(w3c + xo[p] + kldB);
        }
        // 5. barrier: drain LDS writes only, leave global loads in flight
        barrier_lgkm();
        // 6. compute
#pragma unroll
        for (int ks = 0; ks < 2; ++ks) {
            const int kf = ks * 32 + kf0;
            bf16x8 af[4], b1f[4], b3f[4];
#pragma unroll
            for (int m = 0; m < 4; ++m)
                af[m] = *(const bf16x8*)&As[swz(wm * 64 + m * 16 + l15, kf)];
#pragma unroll
            for (int n = 0; n < 4; ++n) {
                b1f[n] = *(const bf16x8*)&B1s[swz(wn * 64 + n * 16 + l15, kf)];
                b3f[n] = *(const bf16x8*)&B3s[swz(wn * 64 + n * 16 + l15, kf)];
            }
            __builtin_amdgcn_s_setprio(1);
#pragma unroll
            for (int n = 0; n < 4; ++n)
#pragma unroll
                for (int m = 0; m < 4; ++m) {
                    acc1[m][n] = MFMA(af[m], b1f[n], acc1[m][n], 0, 0, 0);
                    acc3[m][n] = MFMA(af[m], b3f[n], acc3[m][n], 0, 0, 0);
                }
            __builtin_amdgcn_s_setprio(0);
        }
        // 7. post-compute barrier (reads done before next overwrite)
        barrier_lgkm();
    }

    // epilogue: bias + silu*mul -> bf16 g
    float bias1[4], bias3[4];
#pragma unroll
    for (int n = 0; n < 4; ++n) {
        const int f = bn + wn * 64 + n * 16 + l15;
        bias1[n] = b1[e * DINT + f];
        bias3[n] = b3[e * DINT + f];
    }
#pragma unroll
    for (int m = 0; m < 4; ++m)
#pragma unroll
        for (int n = 0; n < 4; ++n) {
            const int f = bn + wn * 64 + n * 16 + l15;
#pragma unroll
            for (int j = 0; j < 4; ++j) {
                const int t = bm + wm * 64 + m * 16 + ((lane >> 4) << 2) + j;
                const float h1 = acc1[m][n][j] + bias1[n];
                const float h3 = acc3[m][n][j] + bias3[n];
                const float sg = h1 / (1.0f + __expf(-h1));
                g[(size_t)e * NT * DINT + (size_t)t * DINT + f] =
                    __builtin_bit_cast(unsigned short, (__bf16)(sg * h3));
            }
        }
}

// ---------------- Kernel B: down ----------------
// BM=128 x BN=128, BK=64, 256 thr, wave 64x64. Single-buffer 32 KB LDS,
// min 3 waves/EU -> 3 blocks/CU. grid (56,4,8)=1792.
// A staging: 8 threads/row x 8 elems (full 64-elem coverage), 4 passes of
// 32 rows (R7 bug was 4 thr/row x 8 elems = half coverage).
__global__ __launch_bounds__(256, 3) void ffn_down(
    const unsigned short* __restrict__ g, const float* __restrict__ w2,
    const float* __restrict__ b2, float* __restrict__ out) {
    __shared__ unsigned short As[128 * BK];  // 16 KB (g, bf16)
    __shared__ unsigned short Bs[128 * BK];  // 16 KB

    const int tid = threadIdx.x;
    const int lane = tid & 63;
    const int wave = tid >> 6;
    const int wm = wave >> 1, wn = wave & 1;
    const int e = blockIdx.z;
    const int bn = blockIdx.x * 128;
    const int bm = blockIdx.y * 128;

    const char* gc = (const char*)g + ((size_t)e * NT * DINT + (size_t)bm * DINT) * 2;
    const char* w2c = (const char*)w2 + ((size_t)e * DIN * DINT + (size_t)bn * DINT) * 4;

    const int arow = tid >> 3;        // 0..31
    const int acol = (tid & 7) * 8;   // bf16 elems; 8 thr/row x 8 elems = 64
    const int swA = swz(arow, acol);  // p-invariant ((p*32+arow)&7 == arow&7)
    const int srow = tid >> 4;        // 0..15
    const int scol = (tid & 15) * 4;
    const int swB = swz(srow, scol);

    int go[4], wo[8];
#pragma unroll
    for (int p = 0; p < 4; ++p) go[p] = ((p * 32 + arow) * DINT + acol) * 2;
#pragma unroll
    for (int p = 0; p < 8; ++p) wo[p] = ((p * 16 + srow) * DINT + scol) * 4;

    f32x4 acc[4][4];
#pragma unroll
    for (int m = 0; m < 4; ++m)
#pragma unroll
        for (int n = 0; n < 4; ++n) acc[m][n] = (f32x4)0.0f;

    ushort8v ga[4];
    float4 rb[8];

    // prologue: issue tile-0 loads
#pragma unroll
    for (int p = 0; p < 4; ++p) ga[p] = *(const ushort8v*)(gc + go[p]);
#pragma unroll
    for (int p = 0; p < 8; ++p) rb[p] = *(const float4*)(w2c + wo[p]);

    const int l15 = lane & 15;
    const int kf0 = (lane >> 4) << 3;
    const int NIT = DINT / BK;  // 32

    for (int t = 0; t < NIT; ++t) {
        // write tile t
#pragma unroll
        for (int p = 0; p < 4; ++p) *(ushort8v*)&As[p * 2048 + swA] = ga[p];
#pragma unroll
        for (int p = 0; p < 8; ++p) *(ushort4*)&Bs[p * 1024 + swB] = cvt4(rb[p]);
        // issue tile t+1 (in flight across barrier + compute)
        const int kld = ((t + 1 < NIT) ? (t + 1) : (NIT - 1)) * BK;
#pragma unroll
        for (int p = 0; p < 4; ++p) ga[p] = *(const ushort8v*)(gc + go[p] + kld * 2);
#pragma unroll
        for (int p = 0; p < 8; ++p) rb[p] = *(const float4*)(w2c + wo[p] + kld * 4);
        barrier_lgkm();
#pragma unroll
        for (int ks = 0; ks < 2; ++ks) {
            const int kf = ks * 32 + kf0;
            bf16x8 af[4], bf[4];
#pragma unroll
            for (int m = 0; m < 4; ++m)
                af[m] = *(const bf16x8*)&As[swz(wm * 64 + m * 16 + l15, kf)];
#pragma unroll
            for (int n = 0; n < 4; ++n)
                bf[n] = *(const bf16x8*)&Bs[swz(wn * 64 + n * 16 + l15, kf)];
            __builtin_amdgcn_s_setprio(1);
#pragma unroll
            for (int n = 0; n < 4; ++n)
#pragma unroll
                for (int m = 0; m < 4; ++m)
                    acc[m][n] = MFMA(af[m], bf[n], acc[m][n], 0, 0, 0);
            __builtin_amdgcn_s_setprio(0);
        }
        barrier_lgkm();
    }

    float bias[4];
#pragma unroll
    for (int n = 0; n < 4; ++n) {
        const int d = bn + wn * 64 + n * 16 + l15;
        bias[n] = b2[e * DIN + d];
    }
#pragma unroll
    for (int m = 0; m < 4; ++m)
#pragma unroll
        for (int n = 0; n < 4; ++n) {
            const int d = bn + wn * 64 + n * 16 + l15;
#pragma unroll
            for (int j = 0; j < 4; ++j) {
                const int t = bm + wm * 64 + m * 16 + ((lane >> 4) << 2) + j;
                out[(size_t)e * NT * DIN + (size_t)t * DIN + d] = acc[m][n][j] + bias[n];
            }
        }
}

extern "C" void kernel_launch(void* const* d_in, const int* in_sizes, int n_in,
                              void* d_out, int out_size, void* d_ws, size_t ws_size,
                              hipStream_t stream) {
    const float* x = (const float*)d_in[0];
    const float* w1 = (const float*)d_in[1];
    const float* b1 = (const float*)d_in[2];
    const float* w3 = (const float*)d_in[3];
    const float* b3 = (const float*)d_in[4];
    const float* w2 = (const float*)d_in[5];
    const float* b2 = (const float*)d_in[6];
    float* out = (float*)d_out;
    unsigned short* g = (unsigned short*)d_ws;  // [E][T][DINT] bf16

    dim3 gridA(DINT / 128, NT / 128, NE);  // (16, 4, 8) = 512 blocks = 2/CU
    dim3 gridB(DIN / 128, NT / 128, NE);   // (56, 4, 8) = 1792 blocks
    ffn_gate_up<<<gridA, dim3(256), 0, stream>>>(x, w1, b1, w3, b3, g);
    ffn_down<<<gridB, dim3(256), 0, stream>>>(g, w2, b2, out);
}

// Round 9
// 1575.593 us; speedup vs baseline: 1.0176x; 1.0176x over previous
//
#include <hip/hip_runtime.h>
#include <hip/hip_bf16.h>

#define NE 8
#define NT 512
#define DIN 7168
#define DINT 2048
#define BK 64

typedef __bf16 bf16x8 __attribute__((ext_vector_type(8)));
typedef float f32x4 __attribute__((ext_vector_type(4)));
typedef unsigned short ushort8v __attribute__((ext_vector_type(8)));

#define MFMA __builtin_amdgcn_mfma_f32_16x16x32_bf16

// XOR swizzle (T2): 16B granule within a 128B row XOR'd with row&7.
// row stride = 64 bf16 elements (128B).
__device__ __forceinline__ int swz(int row, int k) {
    return (row << 6) + (((k >> 3) ^ (row & 7)) << 3) + (k & 7);
}

__device__ __forceinline__ ushort4 cvt4(float4 v) {
    ushort4 h;
    h.x = __builtin_bit_cast(unsigned short, (__bf16)v.x);
    h.y = __builtin_bit_cast(unsigned short, (__bf16)v.y);
    h.z = __builtin_bit_cast(unsigned short, (__bf16)v.z);
    h.w = __builtin_bit_cast(unsigned short, (__bf16)v.w);
    return h;
}

// lgkm-only drain + raw barrier: outstanding global loads (vmcnt) stay in
// flight across the barrier (T4).
__device__ __forceinline__ void barrier_lgkm() {
    asm volatile("s_waitcnt lgkmcnt(0)" ::: "memory");
    __builtin_amdgcn_s_barrier();
}

// ---------------- Kernel A: gate+up ----------------
// BM=128 x BN=64, BK=64, 256 thr = 4 waves (2x2), wave-tile 64x32, dual acc
// (64 AGPR). Single-buffer LDS 32 KB; __launch_bounds__(256,3) caps regs
// ~170 -> 3 blocks/CU = 12 waves: TLP hides latency (R2-down regime).
// Grid bm-FASTEST: the 4 bm-sharers of each weight panel are consecutive
// blocks -> launched together -> L3 dedupes weight streams (R8 failure fix).
// Iter: issue x(t) -> write w(t) -> issue w(t+1) -> write x(t)
//       -> lgkm barrier -> compute -> lgkm barrier.
__global__ __launch_bounds__(256, 3) void ffn_gate_up(
    const float* __restrict__ x, const float* __restrict__ w1,
    const float* __restrict__ b1, const float* __restrict__ w3,
    const float* __restrict__ b3, unsigned short* __restrict__ g) {
    __shared__ unsigned short As[128 * BK];  // 16 KB
    __shared__ unsigned short B1s[64 * BK];  // 8 KB
    __shared__ unsigned short B3s[64 * BK];  // 8 KB

    const int tid = threadIdx.x;
    const int lane = tid & 63;
    const int wave = tid >> 6;                // 0..3
    const int wm = wave >> 1, wn = wave & 1;  // wave tile 64(M) x 32(N)
    const int e = blockIdx.z;
    const int bm = blockIdx.x * 128;  // token offset (fastest dim)
    const int bn = blockIdx.y * 64;   // F offset

    const char* xb = (const char*)x + ((size_t)e * NT * DIN + (size_t)bm * DIN) * 4;
    const char* w1c = (const char*)w1 + ((size_t)e * DINT * DIN + (size_t)bn * DIN) * 4;
    const char* w3c = (const char*)w3 + ((size_t)e * DINT * DIN + (size_t)bn * DIN) * 4;

    const int srow = tid >> 4;        // 0..15
    const int scol = (tid & 15) * 4;  // 0..60
    const int swb = swz(srow, scol);  // p-invariant ((p*16+srow)&7 == srow&7)

    int xo[8];  // row offsets, shared by x (p=0..7) and w (p=0..3): stride DIN
#pragma unroll
    for (int p = 0; p < 8; ++p) xo[p] = ((p * 16 + srow) * DIN + scol) * 4;

    f32x4 acc1[4][2], acc3[4][2];  // 64 AGPR total
#pragma unroll
    for (int m = 0; m < 4; ++m)
#pragma unroll
        for (int n = 0; n < 2; ++n) {
            acc1[m][n] = (f32x4)0.0f;
            acc3[m][n] = (f32x4)0.0f;
        }

    float4 ra[8], rb1[4], rb3[4];

    // prologue: issue weight loads for tile 0
#pragma unroll
    for (int p = 0; p < 4; ++p) {
        rb1[p] = *(const float4*)(w1c + xo[p]);
        rb3[p] = *(const float4*)(w3c + xo[p]);
    }

    const int l15 = lane & 15;
    const int kf0 = (lane >> 4) << 3;
    const int NIT = DIN / BK;  // 112

    for (int t = 0; t < NIT; ++t) {
        const int kkB = t * BK * 4;
        // 1. issue x loads for tile t (latency covered by w-writes + TLP)
#pragma unroll
        for (int p = 0; p < 8; ++p) ra[p] = *(const float4*)(xb + xo[p] + kkB);
        // 2. write w1,w3 tile t (regs loaded a full iteration ago)
#pragma unroll
        for (int p = 0; p < 4; ++p) {
            *(ushort4*)&B1s[p * 1024 + swb] = cvt4(rb1[p]);
            *(ushort4*)&B3s[p * 1024 + swb] = cvt4(rb3[p]);
        }
        // 3. issue weight loads for tile t+1 (fly across barrier + compute)
        const int kldB = ((t + 1 < NIT) ? (t + 1) : (NIT - 1)) * BK * 4;
#pragma unroll
        for (int p = 0; p < 4; ++p) {
            rb1[p] = *(const float4*)(w1c + xo[p] + kldB);
            rb3[p] = *(const float4*)(w3c + xo[p] + kldB);
        }
        // 4. write x tile t
#pragma unroll
        for (int p = 0; p < 8; ++p) *(ushort4*)&As[p * 1024 + swb] = cvt4(ra[p]);
        // 5. barrier: drain LDS writes only; global loads stay in flight
        barrier_lgkm();
        // 6. compute
#pragma unroll
        for (int ks = 0; ks < 2; ++ks) {
            const int kf = ks * 32 + kf0;
            bf16x8 af[4], b1f[2], b3f[2];
#pragma unroll
            for (int m = 0; m < 4; ++m)
                af[m] = *(const bf16x8*)&As[swz(wm * 64 + m * 16 + l15, kf)];
#pragma unroll
            for (int n = 0; n < 2; ++n) {
                b1f[n] = *(const bf16x8*)&B1s[swz(wn * 32 + n * 16 + l15, kf)];
                b3f[n] = *(const bf16x8*)&B3s[swz(wn * 32 + n * 16 + l15, kf)];
            }
            __builtin_amdgcn_s_setprio(1);
#pragma unroll
            for (int n = 0; n < 2; ++n)
#pragma unroll
                for (int m = 0; m < 4; ++m) {
                    acc1[m][n] = MFMA(af[m], b1f[n], acc1[m][n], 0, 0, 0);
                    acc3[m][n] = MFMA(af[m], b3f[n], acc3[m][n], 0, 0, 0);
                }
            __builtin_amdgcn_s_setprio(0);
        }
        // 7. post-compute barrier (reads done before next overwrite)
        barrier_lgkm();
    }

    // epilogue: bias + silu*mul -> bf16 g
    float bias1[2], bias3[2];
#pragma unroll
    for (int n = 0; n < 2; ++n) {
        const int f = bn + wn * 32 + n * 16 + l15;
        bias1[n] = b1[e * DINT + f];
        bias3[n] = b3[e * DINT + f];
    }
#pragma unroll
    for (int m = 0; m < 4; ++m)
#pragma unroll
        for (int n = 0; n < 2; ++n) {
            const int f = bn + wn * 32 + n * 16 + l15;
#pragma unroll
            for (int j = 0; j < 4; ++j) {
                const int t = bm + wm * 64 + m * 16 + ((lane >> 4) << 2) + j;
                const float h1 = acc1[m][n][j] + bias1[n];
                const float h3 = acc3[m][n][j] + bias3[n];
                const float sg = h1 / (1.0f + __expf(-h1));
                g[(size_t)e * NT * DINT + (size_t)t * DINT + f] =
                    __builtin_bit_cast(unsigned short, (__bf16)(sg * h3));
            }
        }
}

// ---------------- Kernel B: down ----------------
// BM=128 x BN=64, BK=64, 256 thr, 4 waves, wave 64x32, single acc (32 AGPR).
// LDS 24 KB; __launch_bounds__(256,4) caps regs 128 -> 4 blocks/CU = 16
// waves. Both inputs prefetched cross-iter. Grid bm-fastest.
__global__ __launch_bounds__(256, 4) void ffn_down(
    const unsigned short* __restrict__ g, const float* __restrict__ w2,
    const float* __restrict__ b2, float* __restrict__ out) {
    __shared__ unsigned short As[128 * BK];  // 16 KB (g, bf16)
    __shared__ unsigned short Bs[64 * BK];   // 8 KB

    const int tid = threadIdx.x;
    const int lane = tid & 63;
    const int wave = tid >> 6;
    const int wm = wave >> 1, wn = wave & 1;  // wave 64x32
    const int e = blockIdx.z;
    const int bm = blockIdx.x * 128;  // token offset (fastest dim)
    const int bn = blockIdx.y * 64;   // D offset

    const char* gc = (const char*)g + ((size_t)e * NT * DINT + (size_t)bm * DINT) * 2;
    const char* w2c = (const char*)w2 + ((size_t)e * DIN * DINT + (size_t)bn * DINT) * 4;

    const int arow = tid >> 3;        // 0..31
    const int acol = (tid & 7) * 8;   // 8 thr/row x 8 bf16 = full 64 coverage
    const int swA = swz(arow, acol);  // p-invariant ((p*32+arow)&7 == arow&7)
    const int srow = tid >> 4;        // 0..15
    const int scol = (tid & 15) * 4;
    const int swB = swz(srow, scol);

    int go[4], wo[4];
#pragma unroll
    for (int p = 0; p < 4; ++p) {
        go[p] = ((p * 32 + arow) * DINT + acol) * 2;
        wo[p] = ((p * 16 + srow) * DINT + scol) * 4;
    }

    f32x4 acc[4][2];  // 32 AGPR
#pragma unroll
    for (int m = 0; m < 4; ++m)
#pragma unroll
        for (int n = 0; n < 2; ++n) acc[m][n] = (f32x4)0.0f;

    ushort8v ga[4];
    float4 rb[4];

    // prologue: issue tile-0 loads (both operands)
#pragma unroll
    for (int p = 0; p < 4; ++p) ga[p] = *(const ushort8v*)(gc + go[p]);
#pragma unroll
    for (int p = 0; p < 4; ++p) rb[p] = *(const float4*)(w2c + wo[p]);

    const int l15 = lane & 15;
    const int kf0 = (lane >> 4) << 3;
    const int NIT = DINT / BK;  // 32

    for (int t = 0; t < NIT; ++t) {
        // write tile t (regs loaded one iteration ago)
#pragma unroll
        for (int p = 0; p < 4; ++p) *(ushort8v*)&As[p * 2048 + swA] = ga[p];
#pragma unroll
        for (int p = 0; p < 4; ++p) *(ushort4*)&Bs[p * 1024 + swB] = cvt4(rb[p]);
        // issue tile t+1 (in flight across barrier + compute)
        const int kld = ((t + 1 < NIT) ? (t + 1) : (NIT - 1)) * BK;
#pragma unroll
        for (int p = 0; p < 4; ++p) ga[p] = *(const ushort8v*)(gc + go[p] + kld * 2);
#pragma unroll
        for (int p = 0; p < 4; ++p) rb[p] = *(const float4*)(w2c + wo[p] + kld * 4);
        barrier_lgkm();
#pragma unroll
        for (int ks = 0; ks < 2; ++ks) {
            const int kf = ks * 32 + kf0;
            bf16x8 af[4], bf[2];
#pragma unroll
            for (int m = 0; m < 4; ++m)
                af[m] = *(const bf16x8*)&As[swz(wm * 64 + m * 16 + l15, kf)];
#pragma unroll
            for (int n = 0; n < 2; ++n)
                bf[n] = *(const bf16x8*)&Bs[swz(wn * 32 + n * 16 + l15, kf)];
            __builtin_amdgcn_s_setprio(1);
#pragma unroll
            for (int n = 0; n < 2; ++n)
#pragma unroll
                for (int m = 0; m < 4; ++m)
                    acc[m][n] = MFMA(af[m], bf[n], acc[m][n], 0, 0, 0);
            __builtin_amdgcn_s_setprio(0);
        }
        barrier_lgkm();
    }

    float bias[2];
#pragma unroll
    for (int n = 0; n < 2; ++n) {
        const int d = bn + wn * 32 + n * 16 + l15;
        bias[n] = b2[e * DIN + d];
    }
#pragma unroll
    for (int m = 0; m < 4; ++m)
#pragma unroll
        for (int n = 0; n < 2; ++n) {
            const int d = bn + wn * 32 + n * 16 + l15;
#pragma unroll
            for (int j = 0; j < 4; ++j) {
                const int t = bm + wm * 64 + m * 16 + ((lane >> 4) << 2) + j;
                out[(size_t)e * NT * DIN + (size_t)t * DIN + d] = acc[m][n][j] + bias[n];
            }
        }
}

extern "C" void kernel_launch(void* const* d_in, const int* in_sizes, int n_in,
                              void* d_out, int out_size, void* d_ws, size_t ws_size,
                              hipStream_t stream) {
    const float* x = (const float*)d_in[0];
    const float* w1 = (const float*)d_in[1];
    const float* b1 = (const float*)d_in[2];
    const float* w3 = (const float*)d_in[3];
    const float* b3 = (const float*)d_in[4];
    const float* w2 = (const float*)d_in[5];
    const float* b2 = (const float*)d_in[6];
    float* out = (float*)d_out;
    unsigned short* g = (unsigned short*)d_ws;  // [E][T][DINT] bf16

    // bm is the FASTEST grid dim: weight-panel sharers launch consecutively
    dim3 gridA(NT / 128, DINT / 64, NE);  // (4, 32, 8) = 1024 blocks
    dim3 gridB(NT / 128, DIN / 64, NE);   // (4, 112, 8) = 3584 blocks
    ffn_gate_up<<<gridA, dim3(256), 0, stream>>>(x, w1, b1, w3, b3, g);
    ffn_down<<<gridB, dim3(256), 0, stream>>>(g, w2, b2, out);
}

// Round 10
// 523.893 us; speedup vs baseline: 3.0605x; 3.0075x over previous
//
#include <hip/hip_runtime.h>
#include <hip/hip_bf16.h>

#define NE 8
#define NT 512
#define DIN 7168
#define DINT 2048
#define BK 64

typedef __bf16 bf16x8 __attribute__((ext_vector_type(8)));
typedef float f32x4 __attribute__((ext_vector_type(4)));
typedef unsigned short ushort8v __attribute__((ext_vector_type(8)));

#define MFMA __builtin_amdgcn_mfma_f32_16x16x32_bf16

// XOR swizzle (T2): 16B granule within a 128B row XOR'd with row&7.
__device__ __forceinline__ int swz(int row, int k) {
    return (row << 6) + (((k >> 3) ^ (row & 7)) << 3) + (k & 7);
}

__device__ __forceinline__ unsigned short b16(float f) {
    return __builtin_bit_cast(unsigned short, (__bf16)f);
}
__device__ __forceinline__ ushort8v cvt8(float4 a, float4 b) {
    ushort8v h;
    h[0] = b16(a.x); h[1] = b16(a.y); h[2] = b16(a.z); h[3] = b16(a.w);
    h[4] = b16(b.x); h[5] = b16(b.y); h[6] = b16(b.z); h[7] = b16(b.w);
    return h;
}

// m201 phase tail: align waves -> drain LDS -> fence -> prioritized MFMA.
#define PHASE_BAR()                                        \
    __builtin_amdgcn_s_barrier();                          \
    asm volatile("s_waitcnt lgkmcnt(0)" ::: "memory");     \
    __builtin_amdgcn_sched_barrier(0)

// ---------------- Kernel A: gate+up ----------------
// BM=256 x BN=128, BK=64, 512 thr = 8 waves (4x2), wave 64x64, dual acc.
// grid (16,2,8)=256 = 1 block/CU (FETCH-perfect). dbuf 128 KB LDS.
// 4 phases/K-tile, m201 rhythm: {frag reads | 1/4 stage-writes (tile t+1,
// regs loaded a FULL TILE ago) | 1/4 load-issues (tile t+2)} -> s_barrier
// -> lgkmcnt(0) -> setprio(1) 16xMFMA setprio(0) -> s_barrier.
// vmcnt never drained: loads have 4 phases in flight.
__global__ __launch_bounds__(512, 2) void ffn_gate_up(
    const float* __restrict__ x, const float* __restrict__ w1,
    const float* __restrict__ b1, const float* __restrict__ w3,
    const float* __restrict__ b3, unsigned short* __restrict__ g) {
    __shared__ unsigned short As[2][256 * BK];   // 2x32 KB
    __shared__ unsigned short B1s[2][128 * BK];  // 2x16 KB
    __shared__ unsigned short B3s[2][128 * BK];  // 2x16 KB

    const int tid = threadIdx.x;
    const int lane = tid & 63;
    const int wave = tid >> 6;
    const int wm = wave >> 1, wn = wave & 1;  // wave tile 64(M) x 64(N)
    const int e = blockIdx.z;
    const int bn = blockIdx.x * 128;
    const int bm = blockIdx.y * 256;

    const char* xb = (const char*)x + ((size_t)e * NT * DIN + (size_t)bm * DIN) * 4;
    const char* w1c = (const char*)w1 + ((size_t)e * DINT * DIN + (size_t)bn * DIN) * 4;
    const char* w3c = (const char*)w3 + ((size_t)e * DINT * DIN + (size_t)bn * DIN) * 4;

    const int srow = tid >> 3;             // 0..63
    const int sc8 = (tid & 7) * 8;         // elem col (8 fp32 / 8 bf16)
    const int scB = (tid & 7) * 32;        // byte col for fp32 loads
    const int swb = swz(srow, sc8);        // p-invariant: (p*64+srow)&7 == srow&7

    int xoA[4], xoB[2];
#pragma unroll
    for (int p = 0; p < 4; ++p) xoA[p] = (p * 64 + srow) * DIN * 4 + scB;
#pragma unroll
    for (int p = 0; p < 2; ++p) xoB[p] = (p * 64 + srow) * DIN * 4 + scB;

    f32x4 acc1[4][4], acc3[4][4];
#pragma unroll
    for (int m = 0; m < 4; ++m)
#pragma unroll
        for (int n = 0; n < 4; ++n) {
            acc1[m][n] = (f32x4)0.0f;
            acc3[m][n] = (f32x4)0.0f;
        }

    float4 ra[8], rb1[4], rb3[4];

    // ---- prologue: tile0 -> regs -> buf0 ; tile1 -> regs ----
#pragma unroll
    for (int p = 0; p < 4; ++p) {
        ra[2 * p] = *(const float4*)(xb + xoA[p]);
        ra[2 * p + 1] = *(const float4*)(xb + xoA[p] + 16);
    }
#pragma unroll
    for (int p = 0; p < 2; ++p) {
        rb1[2 * p] = *(const float4*)(w1c + xoB[p]);
        rb1[2 * p + 1] = *(const float4*)(w1c + xoB[p] + 16);
        rb3[2 * p] = *(const float4*)(w3c + xoB[p]);
        rb3[2 * p + 1] = *(const float4*)(w3c + xoB[p] + 16);
    }
#pragma unroll
    for (int p = 0; p < 4; ++p)
        *(ushort8v*)&As[0][p * 4096 + swb] = cvt8(ra[2 * p], ra[2 * p + 1]);
#pragma unroll
    for (int p = 0; p < 2; ++p) {
        *(ushort8v*)&B1s[0][p * 4096 + swb] = cvt8(rb1[2 * p], rb1[2 * p + 1]);
        *(ushort8v*)&B3s[0][p * 4096 + swb] = cvt8(rb3[2 * p], rb3[2 * p + 1]);
    }
#pragma unroll
    for (int p = 0; p < 4; ++p) {
        ra[2 * p] = *(const float4*)(xb + xoA[p] + BK * 4);
        ra[2 * p + 1] = *(const float4*)(xb + xoA[p] + BK * 4 + 16);
    }
#pragma unroll
    for (int p = 0; p < 2; ++p) {
        rb1[2 * p] = *(const float4*)(w1c + xoB[p] + BK * 4);
        rb1[2 * p + 1] = *(const float4*)(w1c + xoB[p] + BK * 4 + 16);
        rb3[2 * p] = *(const float4*)(w3c + xoB[p] + BK * 4);
        rb3[2 * p + 1] = *(const float4*)(w3c + xoB[p] + BK * 4 + 16);
    }
    asm volatile("s_waitcnt lgkmcnt(0)" ::: "memory");
    __builtin_amdgcn_s_barrier();

    const int l15 = lane & 15;
    const int kf0 = (lane >> 4) << 3;

    int cur = 0;
    const int NIT = DIN / BK;  // 112
    for (int t = 0; t < NIT; ++t) {
        const int nxt = cur ^ 1;
        const int kldB = ((t + 2 < NIT) ? (t + 2) : (NIT - 1)) * BK * 4;
        const bool stage = (t < NIT - 1);
        bf16x8 af[4], bb[4];

        // ======== PHASE 0: A@ks0 + B1@ks0 -> acc1 ========
#pragma unroll
        for (int m = 0; m < 4; ++m)
            af[m] = *(const bf16x8*)&As[cur][swz(wm * 64 + m * 16 + l15, kf0)];
#pragma unroll
        for (int n = 0; n < 4; ++n)
            bb[n] = *(const bf16x8*)&B1s[cur][swz(wn * 64 + n * 16 + l15, kf0)];
        if (stage) {
            *(ushort8v*)&As[nxt][0 * 4096 + swb] = cvt8(ra[0], ra[1]);
            *(ushort8v*)&As[nxt][1 * 4096 + swb] = cvt8(ra[2], ra[3]);
        }
        ra[0] = *(const float4*)(xb + xoA[0] + kldB);
        ra[1] = *(const float4*)(xb + xoA[0] + kldB + 16);
        ra[2] = *(const float4*)(xb + xoA[1] + kldB);
        ra[3] = *(const float4*)(xb + xoA[1] + kldB + 16);
        PHASE_BAR();
        __builtin_amdgcn_s_setprio(1);
#pragma unroll
        for (int n = 0; n < 4; ++n)
#pragma unroll
            for (int m = 0; m < 4; ++m)
                acc1[m][n] = MFMA(af[m], bb[n], acc1[m][n], 0, 0, 0);
        __builtin_amdgcn_s_setprio(0);
        __builtin_amdgcn_s_barrier();

        // ======== PHASE 1: B3@ks0 -> acc3 (reuse af) ========
#pragma unroll
        for (int n = 0; n < 4; ++n)
            bb[n] = *(const bf16x8*)&B3s[cur][swz(wn * 64 + n * 16 + l15, kf0)];
        if (stage) {
            *(ushort8v*)&As[nxt][2 * 4096 + swb] = cvt8(ra[4], ra[5]);
            *(ushort8v*)&As[nxt][3 * 4096 + swb] = cvt8(ra[6], ra[7]);
        }
        ra[4] = *(const float4*)(xb + xoA[2] + kldB);
        ra[5] = *(const float4*)(xb + xoA[2] + kldB + 16);
        ra[6] = *(const float4*)(xb + xoA[3] + kldB);
        ra[7] = *(const float4*)(xb + xoA[3] + kldB + 16);
        PHASE_BAR();
        __builtin_amdgcn_s_setprio(1);
#pragma unroll
        for (int n = 0; n < 4; ++n)
#pragma unroll
            for (int m = 0; m < 4; ++m)
                acc3[m][n] = MFMA(af[m], bb[n], acc3[m][n], 0, 0, 0);
        __builtin_amdgcn_s_setprio(0);
        __builtin_amdgcn_s_barrier();

        // ======== PHASE 2: A@ks1 + B1@ks1 -> acc1 ========
#pragma unroll
        for (int m = 0; m < 4; ++m)
            af[m] = *(const bf16x8*)&As[cur][swz(wm * 64 + m * 16 + l15, 32 + kf0)];
#pragma unroll
        for (int n = 0; n < 4; ++n)
            bb[n] = *(const bf16x8*)&B1s[cur][swz(wn * 64 + n * 16 + l15, 32 + kf0)];
        if (stage) {
            *(ushort8v*)&B1s[nxt][0 * 4096 + swb] = cvt8(rb1[0], rb1[1]);
            *(ushort8v*)&B1s[nxt][1 * 4096 + swb] = cvt8(rb1[2], rb1[3]);
        }
        rb1[0] = *(const float4*)(w1c + xoB[0] + kldB);
        rb1[1] = *(const float4*)(w1c + xoB[0] + kldB + 16);
        rb1[2] = *(const float4*)(w1c + xoB[1] + kldB);
        rb1[3] = *(const float4*)(w1c + xoB[1] + kldB + 16);
        PHASE_BAR();
        __builtin_amdgcn_s_setprio(1);
#pragma unroll
        for (int n = 0; n < 4; ++n)
#pragma unroll
            for (int m = 0; m < 4; ++m)
                acc1[m][n] = MFMA(af[m], bb[n], acc1[m][n], 0, 0, 0);
        __builtin_amdgcn_s_setprio(0);
        __builtin_amdgcn_s_barrier();

        // ======== PHASE 3: B3@ks1 -> acc3 ========
#pragma unroll
        for (int n = 0; n < 4; ++n)
            bb[n] = *(const bf16x8*)&B3s[cur][swz(wn * 64 + n * 16 + l15, 32 + kf0)];
        if (stage) {
            *(ushort8v*)&B3s[nxt][0 * 4096 + swb] = cvt8(rb3[0], rb3[1]);
            *(ushort8v*)&B3s[nxt][1 * 4096 + swb] = cvt8(rb3[2], rb3[3]);
        }
        rb3[0] = *(const float4*)(w3c + xoB[0] + kldB);
        rb3[1] = *(const float4*)(w3c + xoB[0] + kldB + 16);
        rb3[2] = *(const float4*)(w3c + xoB[1] + kldB);
        rb3[3] = *(const float4*)(w3c + xoB[1] + kldB + 16);
        PHASE_BAR();
        __builtin_amdgcn_s_setprio(1);
#pragma unroll
        for (int n = 0; n < 4; ++n)
#pragma unroll
            for (int m = 0; m < 4; ++m)
                acc3[m][n] = MFMA(af[m], bb[n], acc3[m][n], 0, 0, 0);
        __builtin_amdgcn_s_setprio(0);
        __builtin_amdgcn_s_barrier();

        cur = nxt;
    }

    // epilogue: bias + silu*mul -> bf16 g
    float bias1[4], bias3[4];
#pragma unroll
    for (int n = 0; n < 4; ++n) {
        const int f = bn + wn * 64 + n * 16 + l15;
        bias1[n] = b1[e * DINT + f];
        bias3[n] = b3[e * DINT + f];
    }
#pragma unroll
    for (int m = 0; m < 4; ++m)
#pragma unroll
        for (int n = 0; n < 4; ++n) {
            const int f = bn + wn * 64 + n * 16 + l15;
#pragma unroll
            for (int j = 0; j < 4; ++j) {
                const int t = bm + wm * 64 + m * 16 + ((lane >> 4) << 2) + j;
                const float h1 = acc1[m][n][j] + bias1[n];
                const float h3 = acc3[m][n][j] + bias3[n];
                const float sg = h1 / (1.0f + __expf(-h1));
                g[(size_t)e * NT * DINT + (size_t)t * DINT + f] =
                    __builtin_bit_cast(unsigned short, (__bf16)(sg * h3));
            }
        }
}

// ---------------- Kernel B: down ----------------
// BM=256 x BN=128, BK=64, 512 thr, wave 64x64. grid (56,2,8)=896. dbuf 96 KB.
// 2 phases/K-tile, same m201 rhythm.
__global__ __launch_bounds__(512, 2) void ffn_down(
    const unsigned short* __restrict__ g, const float* __restrict__ w2,
    const float* __restrict__ b2, float* __restrict__ out) {
    __shared__ unsigned short As[2][256 * BK];  // 2x32 KB
    __shared__ unsigned short Bs[2][128 * BK];  // 2x16 KB

    const int tid = threadIdx.x;
    const int lane = tid & 63;
    const int wave = tid >> 6;
    const int wm = wave >> 1, wn = wave & 1;
    const int e = blockIdx.z;
    const int bn = blockIdx.x * 128;
    const int bm = blockIdx.y * 256;

    const char* gc = (const char*)g + ((size_t)e * NT * DINT + (size_t)bm * DINT) * 2;
    const char* w2c = (const char*)w2 + ((size_t)e * DIN * DINT + (size_t)bn * DINT) * 4;

    const int srow = tid >> 3;       // 0..63
    const int sc8 = (tid & 7) * 8;   // elem col
    const int sw8 = swz(srow, sc8);  // p-invariant

    int go[4], wo[2];
#pragma unroll
    for (int p = 0; p < 4; ++p) go[p] = (p * 64 + srow) * DINT * 2 + sc8 * 2;
#pragma unroll
    for (int p = 0; p < 2; ++p) wo[p] = (p * 64 + srow) * DINT * 4 + sc8 * 4;

    f32x4 acc[4][4];
#pragma unroll
    for (int m = 0; m < 4; ++m)
#pragma unroll
        for (int n = 0; n < 4; ++n) acc[m][n] = (f32x4)0.0f;

    ushort8v ga[4];
    float4 rb[4];

    // prologue: tile0 -> regs -> buf0 ; tile1 -> regs
#pragma unroll
    for (int p = 0; p < 4; ++p) ga[p] = *(const ushort8v*)(gc + go[p]);
#pragma unroll
    for (int p = 0; p < 2; ++p) {
        rb[2 * p] = *(const float4*)(w2c + wo[p]);
        rb[2 * p + 1] = *(const float4*)(w2c + wo[p] + 16);
    }
#pragma unroll
    for (int p = 0; p < 4; ++p) *(ushort8v*)&As[0][p * 4096 + sw8] = ga[p];
#pragma unroll
    for (int p = 0; p < 2; ++p)
        *(ushort8v*)&Bs[0][p * 4096 + sw8] = cvt8(rb[2 * p], rb[2 * p + 1]);
#pragma unroll
    for (int p = 0; p < 4; ++p) ga[p] = *(const ushort8v*)(gc + go[p] + BK * 2);
#pragma unroll
    for (int p = 0; p < 2; ++p) {
        rb[2 * p] = *(const float4*)(w2c + wo[p] + BK * 4);
        rb[2 * p + 1] = *(const float4*)(w2c + wo[p] + BK * 4 + 16);
    }
    asm volatile("s_waitcnt lgkmcnt(0)" ::: "memory");
    __builtin_amdgcn_s_barrier();

    const int l15 = lane & 15;
    const int kf0 = (lane >> 4) << 3;

    int cur = 0;
    const int NIT = DINT / BK;  // 32
    for (int t = 0; t < NIT; ++t) {
        const int nxt = cur ^ 1;
        const int kld = ((t + 2 < NIT) ? (t + 2) : (NIT - 1)) * BK;
        const bool stage = (t < NIT - 1);
        bf16x8 af[4], bf[4];

        // ======== PHASE 0: ks0 ========
#pragma unroll
        for (int m = 0; m < 4; ++m)
            af[m] = *(const bf16x8*)&As[cur][swz(wm * 64 + m * 16 + l15, kf0)];
#pragma unroll
        for (int n = 0; n < 4; ++n)
            bf[n] = *(const bf16x8*)&Bs[cur][swz(wn * 64 + n * 16 + l15, kf0)];
        if (stage) {
            *(ushort8v*)&As[nxt][0 * 4096 + sw8] = ga[0];
            *(ushort8v*)&As[nxt][1 * 4096 + sw8] = ga[1];
            *(ushort8v*)&Bs[nxt][0 * 4096 + sw8] = cvt8(rb[0], rb[1]);
        }
        ga[0] = *(const ushort8v*)(gc + go[0] + kld * 2);
        ga[1] = *(const ushort8v*)(gc + go[1] + kld * 2);
        rb[0] = *(const float4*)(w2c + wo[0] + kld * 4);
        rb[1] = *(const float4*)(w2c + wo[0] + kld * 4 + 16);
        PHASE_BAR();
        __builtin_amdgcn_s_setprio(1);
#pragma unroll
        for (int n = 0; n < 4; ++n)
#pragma unroll
            for (int m = 0; m < 4; ++m)
                acc[m][n] = MFMA(af[m], bf[n], acc[m][n], 0, 0, 0);
        __builtin_amdgcn_s_setprio(0);
        __builtin_amdgcn_s_barrier();

        // ======== PHASE 1: ks1 ========
#pragma unroll
        for (int m = 0; m < 4; ++m)
            af[m] = *(const bf16x8*)&As[cur][swz(wm * 64 + m * 16 + l15, 32 + kf0)];
#pragma unroll
        for (int n = 0; n < 4; ++n)
            bf[n] = *(const bf16x8*)&Bs[cur][swz(wn * 64 + n * 16 + l15, 32 + kf0)];
        if (stage) {
            *(ushort8v*)&As[nxt][2 * 4096 + sw8] = ga[2];
            *(ushort8v*)&As[nxt][3 * 4096 + sw8] = ga[3];
            *(ushort8v*)&Bs[nxt][1 * 4096 + sw8] = cvt8(rb[2], rb[3]);
        }
        ga[2] = *(const ushort8v*)(gc + go[2] + kld * 2);
        ga[3] = *(const ushort8v*)(gc + go[3] + kld * 2);
        rb[2] = *(const float4*)(w2c + wo[1] + kld * 4);
        rb[3] = *(const float4*)(w2c + wo[1] + kld * 4 + 16);
        PHASE_BAR();
        __builtin_amdgcn_s_setprio(1);
#pragma unroll
        for (int n = 0; n < 4; ++n)
#pragma unroll
            for (int m = 0; m < 4; ++m)
                acc[m][n] = MFMA(af[m], bf[n], acc[m][n], 0, 0, 0);
        __builtin_amdgcn_s_setprio(0);
        __builtin_amdgcn_s_barrier();

        cur = nxt;
    }

    float bias[4];
#pragma unroll
    for (int n = 0; n < 4; ++n) {
        const int d = bn + wn * 64 + n * 16 + l15;
        bias[n] = b2[e * DIN + d];
    }
#pragma unroll
    for (int m = 0; m < 4; ++m)
#pragma unroll
        for (int n = 0; n < 4; ++n) {
            const int d = bn + wn * 64 + n * 16 + l15;
#pragma unroll
            for (int j = 0; j < 4; ++j) {
                const int t = bm + wm * 64 + m * 16 + ((lane >> 4) << 2) + j;
                out[(size_t)e * NT * DIN + (size_t)t * DIN + d] = acc[m][n][j] + bias[n];
            }
        }
}

extern "C" void kernel_launch(void* const* d_in, const int* in_sizes, int n_in,
                              void* d_out, int out_size, void* d_ws, size_t ws_size,
                              hipStream_t stream) {
    const float* x = (const float*)d_in[0];
    const float* w1 = (const float*)d_in[1];
    const float* b1 = (const float*)d_in[2];
    const float* w3 = (const float*)d_in[3];
    const float* b3 = (const float*)d_in[4];
    const float* w2 = (const float*)d_in[5];
    const float* b2 = (const float*)d_in[6];
    float* out = (float*)d_out;
    unsigned short* g = (unsigned short*)d_ws;  // [E][T][DINT] bf16

    dim3 gridA(DINT / 128, NT / 256, NE);  // (16, 2, 8) = 256 blocks = 1/CU
    dim3 gridB(DIN / 128, NT / 256, NE);   // (56, 2, 8) = 896 blocks
    ffn_gate_up<<<gridA, dim3(512), 0, stream>>>(x, w1, b1, w3, b3, g);
    ffn_down<<<gridB, dim3(512), 0, stream>>>(g, w2, b2, out);
}